// Round 12
// baseline (313.283 us; speedup 1.0000x reference)
//
#include <hip/hip_runtime.h>
#include <hip/hip_bf16.h>

#define NROWS 8192
#define KD    1024

typedef __attribute__((ext_vector_type(8))) short bf16x8;
typedef __attribute__((ext_vector_type(4))) float f32x4;

__device__ unsigned short g_x1n[(size_t)NROWS * KD];
__device__ unsigned short g_x2n[(size_t)NROWS * KD];

__device__ __forceinline__ unsigned short f2bf(float f) {
    union { float f; unsigned u; } x; x.f = f;
    return (unsigned short)((x.u + 0x7fffu + ((x.u >> 16) & 1u)) >> 16);  // RNE
}

__global__ __launch_bounds__(256) void norm_cast_kernel(const float* __restrict__ x1,
                                                        const float* __restrict__ x2) {
    int row = blockIdx.x;
    const float* src;
    unsigned short* dst;
    if (row < NROWS) { src = x1 + (size_t)row * KD;           dst = g_x1n + (size_t)row * KD; }
    else             { src = x2 + (size_t)(row - NROWS) * KD; dst = g_x2n + (size_t)(row - NROWS) * KD; }

    int t = threadIdx.x;
    float4 v = ((const float4*)src)[t];
    float s = v.x * v.x + v.y * v.y + v.z * v.z + v.w * v.w;
    #pragma unroll
    for (int off = 32; off > 0; off >>= 1) s += __shfl_down(s, off);

    __shared__ float red[4];
    if ((t & 63) == 0) red[t >> 6] = s;
    __syncthreads();
    float tot = red[0] + red[1] + red[2] + red[3];
    float inv = 1.0f / fmaxf(sqrtf(tot), 1e-8f);

    ushort4 o;
    o.x = f2bf(v.x * inv); o.y = f2bf(v.y * inv);
    o.z = f2bf(v.z * inv); o.w = f2bf(v.w * inv);
    ((ushort4*)dst)[t] = o;
}

__device__ __forceinline__ void gload_lds16(const unsigned short* g, unsigned short* l) {
    __builtin_amdgcn_global_load_lds((const __attribute__((address_space(1))) void*)g,
                                     (__attribute__((address_space(3))) void*)l,
                                     16, 0, 0);
}

#define BARX() do { asm volatile("" ::: "memory"); __builtin_amdgcn_s_barrier(); \
                    asm volatile("" ::: "memory"); } while (0)
#define DRAIN_LDS() do { asm volatile("s_waitcnt lgkmcnt(0)" ::: "memory"); \
                         __builtin_amdgcn_sched_barrier(0); } while (0)
#define MFMA16(a, b, c) __builtin_amdgcn_mfma_f32_16x16x32_bf16((a), (b), (c), 0, 0, 0)

// 16-MFMA set, kk-outer (8 independent MFMAs between dependent writes).
#define MSET(MI, NI, FA, FB) do {                                              \
    __builtin_amdgcn_s_setprio(1);                                             \
    _Pragma("unroll") for (int k_ = 0; k_ < 2; ++k_)                           \
      _Pragma("unroll") for (int mi_ = 0; mi_ < 4; ++mi_)                      \
        _Pragma("unroll") for (int ni_ = 0; ni_ < 2; ++ni_)                    \
          acc[(MI) + mi_][(NI) + ni_] =                                        \
              MFMA16(FA[mi_][k_], FB[ni_][k_], acc[(MI) + mi_][(NI) + ni_]);   \
    __builtin_amdgcn_s_setprio(0);                                             \
} while (0)

struct Ctx {
    const unsigned short* Ablk;
    const unsigned short* Bblk;
    unsigned short* ldsf;
    int t;
    int trow;                     // t>>3 (staging row 0..63)
    int scol;                     // pre-swizzled source col element offset
    int aoff0, aoff1, boff0, boff1;
    int wr, wch;
};

// Stage one half-tile (128 rows x 64 k): 2 x global_load_lds(16B) per thread.
__device__ __forceinline__ void stage_half(const Ctx& c, const unsigned short* mat,
                                           int hbit, int region, int Tk) {
    const unsigned short* src = mat + (size_t)(hbit * 128 + c.trow) * KD + Tk * 64 + c.scol;
    unsigned short* dst = c.ldsf + region * 8192 + c.t * 8;
    gload_lds16(src, dst);
    gload_lds16(src + (size_t)64 * KD, dst + 4096);
}

#define READ_A(DST, AB, R0_) do {                                              \
    _Pragma("unroll") for (int mi_ = 0; mi_ < 4; ++mi_) {                      \
        DST[mi_][0] = *(const bf16x8*)((AB) + ((R0_) + mi_) * 1024 + c.aoff0); \
        DST[mi_][1] = *(const bf16x8*)((AB) + ((R0_) + mi_) * 1024 + c.aoff1); \
    } } while (0)
#define READ_B(DST, BB, R0_) do {                                              \
    _Pragma("unroll") for (int ni_ = 0; ni_ < 2; ++ni_) {                      \
        DST[ni_][0] = *(const bf16x8*)((BB) + ((R0_) + ni_) * 1024 + c.boff0); \
        DST[ni_][1] = *(const bf16x8*)((BB) + ((R0_) + ni_) * 1024 + c.boff1); \
    } } while (0)

// One K-tile, wave-group role-split: 8 windows; in each, one group reads its
// next fragment set while the other runs a 16-MFMA set (per SIMD: 1 G0 + 1 G1
// wave -> MFMA pipe fed every window, LDS served every window).
// G0 (rdE): R0@w0 M0@w1 R1@w2 M1@w3 R2@w4 M2@w5 -@w6 M3@w7
// G1      : M0@w0 R1@w1 M1@w2 R2@w3 M2@w4 -@w5 M3@w6 R0(T+1)@w7
template<int BUF, bool LAST>
__device__ __forceinline__ void tile_ws(const Ctx& c, f32x4 (&acc)[8][4],
                                        bf16x8 (&A0)[4][2], bf16x8 (&A1)[4][2],
                                        bf16x8 (&B0)[2][2], bf16x8 (&B1)[2][2],
                                        bool rdE, int T) {
    const unsigned short* ab  = c.ldsf + (BUF * 4 + c.wr) * 8192;
    const unsigned short* bb  = c.ldsf + (BUF * 4 + 2 + c.wch) * 8192;
    const unsigned short* abn = c.ldsf + ((BUF ^ 1) * 4 + c.wr) * 8192;
    const unsigned short* bbn = c.ldsf + ((BUF ^ 1) * 4 + 2 + c.wch) * 8192;

    // ---- w0: stage A(T+1); G0: R0 (A03+B01) | G1: M0 ----
    if (!LAST) {
        stage_half(c, c.Ablk, 0, (BUF ^ 1) * 4 + 0, T + 1);
        stage_half(c, c.Ablk, 1, (BUF ^ 1) * 4 + 1, T + 1);
    }
    if (rdE) { READ_B(B0, bb, 0); READ_A(A0, ab, 0); }
    else     { DRAIN_LDS(); MSET(0, 0, A0, B0); }
    BARX();

    // ---- w1: stage B(T+1); G0: M0 | G1: R1 (A47) ----
    if (!LAST) {
        stage_half(c, c.Bblk, 0, (BUF ^ 1) * 4 + 2, T + 1);
        stage_half(c, c.Bblk, 1, (BUF ^ 1) * 4 + 3, T + 1);
    }
    if (rdE) { DRAIN_LDS(); MSET(0, 0, A0, B0); }
    else     { READ_A(A1, ab, 4); }
    BARX();

    // ---- w2: G0: R1 (A47) | G1: M1 ----
    if (rdE) { READ_A(A1, ab, 4); }
    else     { DRAIN_LDS(); MSET(4, 0, A1, B0); }
    BARX();

    // ---- w3: G0: M1 | G1: R2 (B23) ----
    if (rdE) { DRAIN_LDS(); MSET(4, 0, A1, B0); }
    else     { READ_B(B1, bb, 2); }
    BARX();

    // ---- w4: G0: R2 (B23) | G1: M2 ----
    if (rdE) { READ_B(B1, bb, 2); }
    else     { DRAIN_LDS(); MSET(4, 2, A1, B1); }
    BARX();

    // ---- w5: G0: M2 | G1: idle ----
    if (rdE) { DRAIN_LDS(); MSET(4, 2, A1, B1); }
    BARX();

    // ---- w6: G0: idle | G1: M3 ; vmcnt(0) publishes T+1 (loads 5 windows old) ----
    if (!rdE) { DRAIN_LDS(); MSET(0, 2, A0, B1); }
    asm volatile("s_waitcnt vmcnt(0)" ::: "memory");
    BARX();

    // ---- w7: G0: M3 | G1: R0 of T+1 (cross-tile read-ahead) ----
    if (rdE) { DRAIN_LDS(); MSET(0, 2, A0, B1); }
    else if (!LAST) { READ_B(B0, bbn, 0); READ_A(A0, abn, 0); }
    BARX();
}

// 256x256 tile, BK=64, 8 waves (2M x 4N), wave-group role-split schedule.
__global__ __launch_bounds__(512, 2) void gemmws_kernel(float* __restrict__ C) {
    __shared__ unsigned short lds[2][4][8192];   // 128 KiB

    // L2-rectangle XCD mapping (bijective), bn-band pinned per XCD (round 5: FETCH -63%).
    int bid = blockIdx.x;                 // 1024 blocks
    int xcd  = bid & 7;
    int idx  = bid >> 3;
    int rnd  = idx >> 5;
    int j    = idx & 31;
    int rect = rnd * 8 + xcd;
    int bm = (rect >> 2) * 4 + (j >> 3);
    int bn = (rect & 3) * 8 + (j & 7);

    int t = threadIdx.x;
    int lane = t & 63, wid = t >> 6;
    int wr = wid >> 2, wc = wid & 3;
    bool rdE = (wid < 4);                 // G0; SIMD s hosts wid s (G0) + wid s+4 (G1)
    int r = lane & 15;
    int s0 = (lane >> 4) ^ (r & 7);       // swizzled 16B slot, kk=0
    int s1 = s0 ^ 4;                      // kk=1

    Ctx c;
    c.Ablk = g_x1n + (size_t)bm * 256 * KD;
    c.Bblk = g_x2n + (size_t)bn * 256 * KD;
    c.ldsf = &lds[0][0][0];
    c.t = t;
    c.trow = t >> 3;
    c.scol = (((t & 7) ^ ((t >> 3) & 7))) * 8;   // inverse swizzle on global source
    c.aoff0 = r * 64 + s0 * 8;
    c.aoff1 = r * 64 + s1 * 8;
    c.boff0 = ((wc & 1) * 64 + r) * 64 + s0 * 8;
    c.boff1 = ((wc & 1) * 64 + r) * 64 + s1 * 8;
    c.wr = wr;
    c.wch = wc >> 1;

    f32x4 acc[8][4] = {};
    bf16x8 A0[4][2], A1[4][2], B0[2][2], B1[2][2];

    // Prologue: stage tile0 fully; drain; publish; G1 preloads R0(tile0).
    stage_half(c, c.Ablk, 0, 0, 0);
    stage_half(c, c.Ablk, 1, 1, 0);
    stage_half(c, c.Bblk, 0, 2, 0);
    stage_half(c, c.Bblk, 1, 3, 0);
    asm volatile("s_waitcnt vmcnt(0)" ::: "memory");
    BARX();
    if (!rdE) {
        const unsigned short* ab0 = c.ldsf + c.wr * 8192;
        const unsigned short* bb0 = c.ldsf + (2 + c.wch) * 8192;
        READ_B(B0, bb0, 0); READ_A(A0, ab0, 0);
    }
    BARX();

    for (int it = 0; it < 7; ++it) {      // tiles 0..13 (stage 1..14)
        tile_ws<0, false>(c, acc, A0, A1, B0, B1, rdE, 2 * it);
        tile_ws<1, false>(c, acc, A0, A1, B0, B1, rdE, 2 * it + 1);
    }
    tile_ws<0, false>(c, acc, A0, A1, B0, B1, rdE, 14);   // stages 15
    tile_ws<1, true >(c, acc, A0, A1, B0, B1, rdE, 15);

    // Epilogue: C/D layout col = lane&15, row = (lane>>4)*4 + j.
    int cn = lane & 15, rq = (lane >> 4) * 4;
    int rbase = bm * 256 + wr * 128;
    int cbase = bn * 256 + wc * 64;
    #pragma unroll
    for (int mi = 0; mi < 8; ++mi)
        #pragma unroll
        for (int ni = 0; ni < 4; ++ni)
            #pragma unroll
            for (int j2 = 0; j2 < 4; ++j2)
                C[(size_t)(rbase + mi * 16 + rq + j2) * NROWS + cbase + ni * 16 + cn] =
                    acc[mi][ni][j2] * 20.0f;
}

extern "C" void kernel_launch(void* const* d_in, const int* in_sizes, int n_in,
                              void* d_out, int out_size, void* d_ws, size_t ws_size,
                              hipStream_t stream) {
    (void)in_sizes; (void)n_in; (void)d_ws; (void)ws_size; (void)out_size;
    const float* x1 = (const float*)d_in[0];
    const float* x2 = (const float*)d_in[1];
    float* out = (float*)d_out;

    norm_cast_kernel<<<2 * NROWS, 256, 0, stream>>>(x1, x2);
    gemmws_kernel<<<(NROWS / 256) * (NROWS / 256), 512, 0, stream>>>(out);
}

// Round 13
// 175.489 us; speedup vs baseline: 1.7852x; 1.7852x over previous
//
#include <hip/hip_runtime.h>
#include <hip/hip_bf16.h>

#define NROWS 8192
#define KD    1024

typedef __attribute__((ext_vector_type(8))) short bf16x8;
typedef __attribute__((ext_vector_type(4))) float f32x4;

__device__ unsigned short g_x1n[(size_t)NROWS * KD];
__device__ unsigned short g_x2n[(size_t)NROWS * KD];

__device__ __forceinline__ unsigned short f2bf(float f) {
    union { float f; unsigned u; } x; x.f = f;
    return (unsigned short)((x.u + 0x7fffu + ((x.u >> 16) & 1u)) >> 16);  // RNE
}

__global__ __launch_bounds__(256) void norm_cast_kernel(const float* __restrict__ x1,
                                                        const float* __restrict__ x2) {
    int row = blockIdx.x;
    const float* src;
    unsigned short* dst;
    if (row < NROWS) { src = x1 + (size_t)row * KD;           dst = g_x1n + (size_t)row * KD; }
    else             { src = x2 + (size_t)(row - NROWS) * KD; dst = g_x2n + (size_t)(row - NROWS) * KD; }

    int t = threadIdx.x;
    float4 v = ((const float4*)src)[t];
    float s = v.x * v.x + v.y * v.y + v.z * v.z + v.w * v.w;
    #pragma unroll
    for (int off = 32; off > 0; off >>= 1) s += __shfl_down(s, off);

    __shared__ float red[4];
    if ((t & 63) == 0) red[t >> 6] = s;
    __syncthreads();
    float tot = red[0] + red[1] + red[2] + red[3];
    float inv = 1.0f / fmaxf(sqrtf(tot), 1e-8f);

    ushort4 o;
    o.x = f2bf(v.x * inv); o.y = f2bf(v.y * inv);
    o.z = f2bf(v.z * inv); o.w = f2bf(v.w * inv);
    ((ushort4*)dst)[t] = o;
}

__device__ __forceinline__ void gload_lds16(const unsigned short* g, unsigned short* l) {
    __builtin_amdgcn_global_load_lds((const __attribute__((address_space(1))) void*)g,
                                     (__attribute__((address_space(3))) void*)l,
                                     16, 0, 0);
}

#define BARX() do { asm volatile("" ::: "memory"); __builtin_amdgcn_s_barrier(); \
                    asm volatile("" ::: "memory"); } while (0)
// Template-exact drain: lgkmcnt(0) hint WITHOUT sched_barrier(0). The ds_reads
// are compiler-visible loads, so the compiler's own fine-grained lgkmcnt(N)
// covers the MFMA dependencies; no sched_barrier -> it may start MFMAs on
// early-arrived fragments (the overlap mechanism m201 relies on).
#define DRAIN_LDS() asm volatile("s_waitcnt lgkmcnt(0)" ::: "memory")
#define MFMA16(a, b, c) __builtin_amdgcn_mfma_f32_16x16x32_bf16((a), (b), (c), 0, 0, 0)

struct Ctx {
    const unsigned short* Ablk;
    const unsigned short* Bblk;
    unsigned short* ldsf;
    int t;
    int trow;                     // t>>3 (staging row 0..63)
    int scol;                     // pre-swizzled source col element offset
    int aoff0, aoff1, boff0, boff1;
    int wr, wch;
};

// Stage one half-tile (128 rows x 64 k): 2 x global_load_lds(16B) per thread.
__device__ __forceinline__ void stage_half(const Ctx& c, const unsigned short* mat,
                                           int hbit, int region, int Tk) {
    const unsigned short* src = mat + (size_t)(hbit * 128 + c.trow) * KD + Tk * 64 + c.scol;
    unsigned short* dst = c.ldsf + region * 8192 + c.t * 8;
    gload_lds16(src, dst);
    gload_lds16(src + (size_t)64 * KD, dst + 4096);
}

// One K-tile (BK=64): 4 phases (C-quadrants), 16 MFMA each, kk-OUTER ordering
// (8 independent MFMAs between dependent accumulator reuses).
// Stage: q0 -> (T+1).A0, q1 -> (T+1).A1, q2 -> (T+2).B0, q3 -> (T+2).B1
template<int BUF, bool SA, bool SB, int WAITN>
__device__ __forceinline__ void tile_body(const Ctx& c, f32x4 (&acc)[8][4], int T) {
    const unsigned short* ab = c.ldsf + (BUF * 4 + 0) * 8192 + c.wr * 8192;
    const unsigned short* bb = c.ldsf + (BUF * 4 + 2) * 8192 + c.wch * 8192;
    bf16x8 Af[8], Bf[8];

    // ---- q0: read A mi0-3 (8) + B ni0-1 (4); MFMA mi0-3 x ni0-1 ----
    #pragma unroll
    for (int mi = 0; mi < 4; ++mi) {
        Af[mi * 2 + 0] = *(const bf16x8*)(ab + mi * 1024 + c.aoff0);
        Af[mi * 2 + 1] = *(const bf16x8*)(ab + mi * 1024 + c.aoff1);
    }
    #pragma unroll
    for (int ni = 0; ni < 2; ++ni) {
        Bf[ni * 2 + 0] = *(const bf16x8*)(bb + ni * 1024 + c.boff0);
        Bf[ni * 2 + 1] = *(const bf16x8*)(bb + ni * 1024 + c.boff1);
    }
    if (SA) stage_half(c, c.Ablk, 0, ((BUF ^ 1) * 4 + 0), T + 1);
    asm volatile("s_waitcnt lgkmcnt(8)" ::: "memory");   // 12-read phase pacing hint
    BARX();
    DRAIN_LDS();
    __builtin_amdgcn_s_setprio(1);
    #pragma unroll
    for (int k = 0; k < 2; ++k)
        #pragma unroll
        for (int mi = 0; mi < 4; ++mi)
            #pragma unroll
            for (int ni = 0; ni < 2; ++ni)
                acc[mi][ni] = MFMA16(Af[mi * 2 + k], Bf[ni * 2 + k], acc[mi][ni]);
    __builtin_amdgcn_s_setprio(0);
    BARX();

    // ---- q1: read B ni2-3 (4); MFMA mi0-3 x ni2-3 ----
    #pragma unroll
    for (int ni = 2; ni < 4; ++ni) {
        Bf[ni * 2 + 0] = *(const bf16x8*)(bb + ni * 1024 + c.boff0);
        Bf[ni * 2 + 1] = *(const bf16x8*)(bb + ni * 1024 + c.boff1);
    }
    if (SA) stage_half(c, c.Ablk, 1, ((BUF ^ 1) * 4 + 1), T + 1);
    BARX();
    DRAIN_LDS();
    __builtin_amdgcn_s_setprio(1);
    #pragma unroll
    for (int k = 0; k < 2; ++k)
        #pragma unroll
        for (int mi = 0; mi < 4; ++mi)
            #pragma unroll
            for (int ni = 2; ni < 4; ++ni)
                acc[mi][ni] = MFMA16(Af[mi * 2 + k], Bf[ni * 2 + k], acc[mi][ni]);
    __builtin_amdgcn_s_setprio(0);
    BARX();

    // ---- q2: read A mi4-7 (8, overwrite Af); MFMA mi4-7 x ni2-3 ----
    #pragma unroll
    for (int mi = 0; mi < 4; ++mi) {
        Af[mi * 2 + 0] = *(const bf16x8*)(ab + (mi + 4) * 1024 + c.aoff0);
        Af[mi * 2 + 1] = *(const bf16x8*)(ab + (mi + 4) * 1024 + c.aoff1);
    }
    if (SB) stage_half(c, c.Bblk, 0, (BUF * 4 + 2), T + 2);
    BARX();
    DRAIN_LDS();
    __builtin_amdgcn_s_setprio(1);
    #pragma unroll
    for (int k = 0; k < 2; ++k)
        #pragma unroll
        for (int mi = 0; mi < 4; ++mi)
            #pragma unroll
            for (int ni = 2; ni < 4; ++ni)
                acc[mi + 4][ni] = MFMA16(Af[mi * 2 + k], Bf[ni * 2 + k], acc[mi + 4][ni]);
    __builtin_amdgcn_s_setprio(0);
    BARX();

    // ---- q3: 0 reads; MFMA mi4-7 x ni0-1 ----
    if (SB) stage_half(c, c.Bblk, 1, (BUF * 4 + 3), T + 2);
    BARX();
    DRAIN_LDS();
    __builtin_amdgcn_s_setprio(1);
    #pragma unroll
    for (int k = 0; k < 2; ++k)
        #pragma unroll
        for (int mi = 0; mi < 4; ++mi)
            #pragma unroll
            for (int ni = 0; ni < 2; ++ni)
                acc[mi + 4][ni] = MFMA16(Af[mi * 2 + k], Bf[ni * 2 + k], acc[mi + 4][ni]);
    __builtin_amdgcn_s_setprio(0);
    if (WAITN == 4)      asm volatile("s_waitcnt vmcnt(4)" ::: "memory");
    else if (WAITN == 0) asm volatile("s_waitcnt vmcnt(0)" ::: "memory");
    BARX();
}

// 256x256 tile, BK=64, 8 waves (2M x 4N), 8-phase counted-vmcnt schedule.
__global__ __launch_bounds__(512, 2) void gemm8_kernel(float* __restrict__ C) {
    __shared__ unsigned short lds[2][4][8192];   // 128 KiB

    // L2-rectangle XCD mapping (bijective), bn-band pinned per XCD (round 5: FETCH -63%).
    int bid = blockIdx.x;                 // 1024 blocks
    int xcd  = bid & 7;
    int idx  = bid >> 3;
    int rnd  = idx >> 5;
    int j    = idx & 31;
    int rect = rnd * 8 + xcd;
    int bm = (rect >> 2) * 4 + (j >> 3);
    int bn = (rect & 3) * 8 + (j & 7);

    int t = threadIdx.x;
    int lane = t & 63, wid = t >> 6;
    int wr = wid >> 2, wc = wid & 3;
    int r = lane & 15;
    int s0 = (lane >> 4) ^ (r & 7);       // swizzled 16B slot, kk=0
    int s1 = s0 ^ 4;                      // kk=1

    Ctx c;
    c.Ablk = g_x1n + (size_t)bm * 256 * KD;
    c.Bblk = g_x2n + (size_t)bn * 256 * KD;
    c.ldsf = &lds[0][0][0];
    c.t = t;
    c.trow = t >> 3;
    c.scol = (((t & 7) ^ ((t >> 3) & 7))) * 8;   // inverse swizzle on global source
    c.aoff0 = r * 64 + s0 * 8;
    c.aoff1 = r * 64 + s1 * 8;
    c.boff0 = ((wc & 1) * 64 + r) * 64 + s0 * 8;
    c.boff1 = ((wc & 1) * 64 + r) * 64 + s1 * 8;
    c.wr = wr;
    c.wch = wc >> 1;

    f32x4 acc[8][4] = {};

    // Prologue: tile0 {B0,B1,A0,A1}, tile1 {B0,B1}; wait tile0 complete.
    stage_half(c, c.Bblk, 0, 2, 0);
    stage_half(c, c.Bblk, 1, 3, 0);
    stage_half(c, c.Ablk, 0, 0, 0);
    stage_half(c, c.Ablk, 1, 1, 0);
    stage_half(c, c.Bblk, 0, 6, 1);
    stage_half(c, c.Bblk, 1, 7, 1);
    asm volatile("s_waitcnt vmcnt(4)" ::: "memory");
    BARX();

    for (int it = 0; it < 7; ++it) {      // tiles 0..13, full staging
        tile_body<0, true, true, 4>(c, acc, 2 * it);
        tile_body<1, true, true, 4>(c, acc, 2 * it + 1);
    }
    tile_body<0, true, false, 0>(c, acc, 14);   // stages (15).A0/A1, drain
    tile_body<1, false, false, -1>(c, acc, 15);

    // Epilogue: C/D layout col = lane&15, row = (lane>>4)*4 + j.
    int cn = lane & 15, rq = (lane >> 4) * 4;
    int rbase = bm * 256 + wr * 128;
    int cbase = bn * 256 + wc * 64;
    #pragma unroll
    for (int mi = 0; mi < 8; ++mi)
        #pragma unroll
        for (int ni = 0; ni < 4; ++ni)
            #pragma unroll
            for (int j2 = 0; j2 < 4; ++j2)
                C[(size_t)(rbase + mi * 16 + rq + j2) * NROWS + cbase + ni * 16 + cn] =
                    acc[mi][ni][j2] * 20.0f;
}

extern "C" void kernel_launch(void* const* d_in, const int* in_sizes, int n_in,
                              void* d_out, int out_size, void* d_ws, size_t ws_size,
                              hipStream_t stream) {
    (void)in_sizes; (void)n_in; (void)d_ws; (void)ws_size; (void)out_size;
    const float* x1 = (const float*)d_in[0];
    const float* x2 = (const float*)d_in[1];
    float* out = (float*)d_out;

    norm_cast_kernel<<<2 * NROWS, 256, 0, stream>>>(x1, x2);
    gemm8_kernel<<<(NROWS / 256) * (NROWS / 256), 512, 0, stream>>>(out);
}